// Round 11
// baseline (51.436 us; speedup 1.0000x reference)
//
#include <hip/hip_runtime.h>
#include <math.h>

namespace {
constexpr int R_RUNS  = 4096;
constexpr int T_STEPS = 2048;
constexpr int TBW     = 64;              // timesteps per wave (lane = t)
constexpr int RPW     = 16;              // runs per wave (KB)
constexpr int NTB     = T_STEPS / TBW;   // 32 t-blocks
constexpr int NRG     = R_RUNS / RPW;    // 256 r-groups
}

__device__ __forceinline__ float sigmoidf_(float x) {
    return 1.0f / (1.0f + expf(-x));
}

// gh^e, e in [0,63], branchless binary exponentiation
__device__ __forceinline__ float powg(float gh, int e) {
    float w = 1.0f, p = gh;
    #pragma unroll
    for (int i = 0; i < 6; ++i) {
        w *= ((e >> i) & 1) ? p : 1.0f;
        p *= p;
    }
    return w;
}

// ---------------------------------------------------------------------------
// K1: 32 waves (8 blocks). Wave w builds W[t] = sum_{s<t} gh^{t-1-s} z_s for
// t in [64w, 64w+64), gh = sigmoid(G[0]):
//   prefix: lane L Horner-sums rows s = L+64m (m<w) with ratio gh^64,
//           scale gh^{63-L}, butterfly-reduce -> W_{t0} on all lanes;
//   local:  6-step Hillis-Steele weighted scan of the wave's own z rows;
//   W_t = gh^lane * W_{t0} + I_{lane-1}.  (verified exact in R10)
// ---------------------------------------------------------------------------
extern "C" __global__ __launch_bounds__(256)
void dlm_k1_w(const float* __restrict__ Zt, const float* __restrict__ G,
              float* __restrict__ W)
{
    const int tid  = threadIdx.x;
    const int wid  = tid >> 6;
    const int lane = tid & 63;
    const int wv   = blockIdx.x * 4 + wid;   // chunk 0..31
    const int t0   = wv * TBW;
    const int t    = t0 + lane;

    const float gh = sigmoidf_(G[0]);
    float gh64 = gh;
    #pragma unroll
    for (int i = 0; i < 6; ++i) gh64 *= gh64;

    const float4 za = *reinterpret_cast<const float4*>(Zt + (size_t)t * 8);
    const float4 zb = *reinterpret_cast<const float4*>(Zt + (size_t)t * 8 + 4);

    // ---- prefix part
    float acc[8] = {0.f, 0.f, 0.f, 0.f, 0.f, 0.f, 0.f, 0.f};
    for (int m = 0; m < wv; ++m) {
        const float* __restrict__ zp = Zt + (size_t)(m * 64 + lane) * 8;
        const float4 pa = *reinterpret_cast<const float4*>(zp);
        const float4 pb = *reinterpret_cast<const float4*>(zp + 4);
        acc[0] = fmaf(gh64, acc[0], pa.x);
        acc[1] = fmaf(gh64, acc[1], pa.y);
        acc[2] = fmaf(gh64, acc[2], pa.z);
        acc[3] = fmaf(gh64, acc[3], pa.w);
        acc[4] = fmaf(gh64, acc[4], pb.x);
        acc[5] = fmaf(gh64, acc[5], pb.y);
        acc[6] = fmaf(gh64, acc[6], pb.z);
        acc[7] = fmaf(gh64, acc[7], pb.w);
    }
    const float wl = powg(gh, 63 - lane);
    #pragma unroll
    for (int i = 0; i < 8; ++i) acc[i] *= wl;
    #pragma unroll
    for (int d = 1; d < 64; d <<= 1) {
        #pragma unroll
        for (int i = 0; i < 8; ++i)
            acc[i] += __shfl_xor(acc[i], d, 64);
    }

    // ---- local weighted inclusive scan
    float I[8] = {za.x, za.y, za.z, za.w, zb.x, zb.y, zb.z, zb.w};
    float p = gh;
    #pragma unroll
    for (int d = 1; d < 64; d <<= 1) {
        #pragma unroll
        for (int i = 0; i < 8; ++i) {
            const float up = __shfl_up(I[i], (unsigned)d, 64);
            if (lane >= d) I[i] = fmaf(p, up, I[i]);
        }
        p *= p;
    }

    // ---- W_t and store
    const float wj = powg(gh, lane);
    float Wt[8];
    #pragma unroll
    for (int i = 0; i < 8; ++i) {
        const float L = __shfl_up(I[i], 1u, 64);
        Wt[i] = fmaf(wj, acc[i], (lane == 0) ? 0.0f : L);
    }
    *reinterpret_cast<float4*>(W + (size_t)t * 8)     = make_float4(Wt[0], Wt[1], Wt[2], Wt[3]);
    *reinterpret_cast<float4*>(W + (size_t)t * 8 + 4) = make_float4(Wt[4], Wt[5], Wt[6], Wt[7]);
}

// ---------------------------------------------------------------------------
// KB: pure rank-24 GEMM. 8192 waves (8/SIMD). lane = t, 16 runs per wave.
//   out[r][t] = eta_r.x_t + zeta_r.z_t + gamma_r.W_t
// x/z/W per-lane coalesced VMEM; params wave-uniform s_load; direct
// 256B-coalesced stores. No LDS, no shuffles, no recurrence.
// Fallback (any of the wave's G's != G[0]): exact serial replay from t=0.
// ---------------------------------------------------------------------------
extern "C" __global__ __launch_bounds__(256, 8)
void dlm_kb(const float* __restrict__ Xt, const float* __restrict__ Zt,
            const float* __restrict__ G, const float* __restrict__ eta,
            const float* __restrict__ zeta, const float* __restrict__ gamma,
            const float* __restrict__ W, float* __restrict__ out)
{
    const int tid  = threadIdx.x;
    const int wid  = tid >> 6;
    const int lane = tid & 63;
    const int wave = blockIdx.x * 4 + wid;   // 0..8191
    const int tb   = wave & (NTB - 1);       // 0..31
    const int rg   = wave >> 5;              // 0..255
    const int t0   = tb * TBW;
    const int r0   = rg * RPW;
    const int t    = t0 + lane;

    const float4 xa = *reinterpret_cast<const float4*>(Xt + (size_t)t * 8);
    const float4 xb = *reinterpret_cast<const float4*>(Xt + (size_t)t * 8 + 4);
    const float4 za = *reinterpret_cast<const float4*>(Zt + (size_t)t * 8);
    const float4 zb = *reinterpret_cast<const float4*>(Zt + (size_t)t * 8 + 4);
    const float4 wa = *reinterpret_cast<const float4*>(W  + (size_t)t * 8);
    const float4 wb = *reinterpret_cast<const float4*>(W  + (size_t)t * 8 + 4);

    const float G0  = G[0];
    const float gv  = G[r0 + (lane & (RPW - 1))];
    const bool  uni = (__ballot(gv == G0) == ~0ull);

    if (uni) {
        #pragma unroll
        for (int rr = 0; rr < RPW; ++rr) {
            const float* __restrict__ e  = eta   + (size_t)(r0 + rr) * 8;  // uniform
            const float* __restrict__ zc = zeta  + (size_t)(r0 + rr) * 8;  // uniform
            const float* __restrict__ gc = gamma + (size_t)(r0 + rr) * 8;  // uniform
            float s = xa.x * e[0];
            s = fmaf(xa.y, e[1], s);
            s = fmaf(xa.z, e[2], s);
            s = fmaf(xa.w, e[3], s);
            s = fmaf(xb.x, e[4], s);
            s = fmaf(xb.y, e[5], s);
            s = fmaf(xb.z, e[6], s);
            s = fmaf(xb.w, e[7], s);
            s = fmaf(za.x, zc[0], s);
            s = fmaf(za.y, zc[1], s);
            s = fmaf(za.z, zc[2], s);
            s = fmaf(za.w, zc[3], s);
            s = fmaf(zb.x, zc[4], s);
            s = fmaf(zb.y, zc[5], s);
            s = fmaf(zb.z, zc[6], s);
            s = fmaf(zb.w, zc[7], s);
            s = fmaf(wa.x, gc[0], s);
            s = fmaf(wa.y, gc[1], s);
            s = fmaf(wa.z, gc[2], s);
            s = fmaf(wa.w, gc[3], s);
            s = fmaf(wb.x, gc[4], s);
            s = fmaf(wb.y, gc[5], s);
            s = fmaf(wb.z, gc[6], s);
            s = fmaf(wb.w, gc[7], s);
            out[(size_t)(r0 + rr) * T_STEPS + t] = s;
        }
    } else {
        // exact, slow fallback: serial replay from t=0 (correctness-only)
        for (int rr = 0; rr < RPW; ++rr) {
            const int r = r0 + rr;
            const float ghr = sigmoidf_(G[r]);
            const float* __restrict__ gc = gamma + (size_t)r * 8;  // uniform
            const float* __restrict__ e  = eta   + (size_t)r * 8;  // uniform
            const float* __restrict__ zc = zeta  + (size_t)r * 8;  // uniform
            float th = 0.0f, mine = 0.0f;
            for (int s2 = 1; s2 <= t0 + 63; ++s2) {
                const float* __restrict__ zr = Zt + (size_t)(s2 - 1) * 8;  // uniform
                float b = zr[0] * gc[0];
                #pragma unroll
                for (int q = 1; q < 8; ++q) b = fmaf(zr[q], gc[q], b);
                th = fmaf(ghr, th, b);
                mine = (s2 == t) ? th : mine;
            }
            float s = mine;
            s = fmaf(xa.x, e[0], s);  s = fmaf(xa.y, e[1], s);
            s = fmaf(xa.z, e[2], s);  s = fmaf(xa.w, e[3], s);
            s = fmaf(xb.x, e[4], s);  s = fmaf(xb.y, e[5], s);
            s = fmaf(xb.z, e[6], s);  s = fmaf(xb.w, e[7], s);
            s = fmaf(za.x, zc[0], s); s = fmaf(za.y, zc[1], s);
            s = fmaf(za.z, zc[2], s); s = fmaf(za.w, zc[3], s);
            s = fmaf(zb.x, zc[4], s); s = fmaf(zb.y, zc[5], s);
            s = fmaf(zb.z, zc[6], s); s = fmaf(zb.w, zc[7], s);
            out[(size_t)r * T_STEPS + t] = s;
        }
    }
}

// ---------------------------------------------------------------------------
extern "C" void kernel_launch(void* const* d_in, const int* in_sizes, int n_in,
                              void* d_out, int out_size, void* d_ws, size_t ws_size,
                              hipStream_t stream)
{
    const float* Xt    = (const float*)d_in[0];
    const float* Zt    = (const float*)d_in[1];
    const float* G     = (const float*)d_in[2];
    const float* eta   = (const float*)d_in[3];
    const float* zeta  = (const float*)d_in[4];
    const float* gamma = (const float*)d_in[5];
    float* out = (float*)d_out;

    float* W = (float*)d_ws;                  // W[2048][8], 64 KB

    const dim3 blk(256);
    dlm_k1_w<<<dim3(NTB / 4),        blk, 0, stream>>>(Zt, G, W);       // 8 blocks
    dlm_kb  <<<dim3(NTB * NRG / 4),  blk, 0, stream>>>(Xt, Zt, G, eta, zeta, gamma, W, out);  // 2048 blocks
}

// Round 12
// 26.790 us; speedup vs baseline: 1.9199x; 1.9199x over previous
//
#include <hip/hip_runtime.h>
#include <math.h>

typedef float  f32x4  __attribute__((ext_vector_type(4)));
typedef short  bf16x8 __attribute__((ext_vector_type(8)));

namespace {
constexpr int R_RUNS  = 4096;
constexpr int T_STEPS = 2048;
constexpr int NKS     = 3;   // three K=32 MFMA steps (K=96, 72 used)
constexpr size_t PA_ELEMS = (size_t)(R_RUNS / 16) * NKS * 4 * 16 * 8;  // 393216 ushort
}

__device__ __forceinline__ float sigmoidf_(float x) { return 1.0f / (1.0f + expf(-x)); }

// f32 -> bf16 (RNE) and back, bit-level (no lib dependency)
__device__ __forceinline__ unsigned short f2bf(float f) {
    unsigned u = __float_as_uint(f);
    unsigned r = (u + 0x7FFFu + ((u >> 16) & 1u)) >> 16;
    return (unsigned short)r;
}
__device__ __forceinline__ float bf2f(unsigned short h) {
    return __uint_as_float(((unsigned)h) << 16);
}
__device__ __forceinline__ float powg(float gh, int e) {   // gh^e, e in [0,63]
    float w = 1.f, p = gh;
    #pragma unroll
    for (int i = 0; i < 6; ++i) { w *= ((e >> i) & 1) ? p : 1.f; p *= p; }
    return w;
}

// ---------------------------------------------------------------------------
// K1 (8 blocks, 32 waves): wave wv owns t in [64wv, 64wv+64), lane = t.
//  1) W_t scan (verified R10/R11 code): prefix Horner + butterfly + local
//     Hillis-Steele weighted scan.
//  2) Pack Qb[t-tile][s][ko][col][8] bf16: B k-column [Qhi|Qlo|Qhi|0] of
//     Q_t = [x_t|z_t|W_t].
//  3) Pack Pa[r-tile][s][ko][row][8] bf16: A k-row [Phi|Phi|Plo|0] of
//     P_r = [eta_r|zeta_r|gamma_r]  (128 rows per wave, 2 per lane).
// Fragment order: lane l reads octet ko=l>>4, row/col=l&15 as one dwordx4.
// ---------------------------------------------------------------------------
extern "C" __global__ __launch_bounds__(256)
void dlm_k1_pack(const float* __restrict__ Xt, const float* __restrict__ Zt,
                 const float* __restrict__ G, const float* __restrict__ eta,
                 const float* __restrict__ zeta, const float* __restrict__ gamma,
                 unsigned short* __restrict__ Pa, unsigned short* __restrict__ Qb)
{
    const int tid  = threadIdx.x;
    const int wid  = tid >> 6;
    const int lane = tid & 63;
    const int wv   = blockIdx.x * 4 + wid;   // 0..31
    const int t    = wv * 64 + lane;

    const float gh = sigmoidf_(G[0]);
    float gh64 = gh;
    #pragma unroll
    for (int i = 0; i < 6; ++i) gh64 *= gh64;

    const float4 za = *reinterpret_cast<const float4*>(Zt + (size_t)t * 8);
    const float4 zb = *reinterpret_cast<const float4*>(Zt + (size_t)t * 8 + 4);
    const float4 xa = *reinterpret_cast<const float4*>(Xt + (size_t)t * 8);
    const float4 xb = *reinterpret_cast<const float4*>(Xt + (size_t)t * 8 + 4);

    // ---- W prefix: lane L Horner-sums rows s = L+64m (m<wv), ratio gh^64
    float acc[8] = {0.f, 0.f, 0.f, 0.f, 0.f, 0.f, 0.f, 0.f};
    for (int m = 0; m < wv; ++m) {
        const float* __restrict__ zp = Zt + (size_t)(m * 64 + lane) * 8;
        const float4 pa = *reinterpret_cast<const float4*>(zp);
        const float4 pb = *reinterpret_cast<const float4*>(zp + 4);
        acc[0] = fmaf(gh64, acc[0], pa.x);
        acc[1] = fmaf(gh64, acc[1], pa.y);
        acc[2] = fmaf(gh64, acc[2], pa.z);
        acc[3] = fmaf(gh64, acc[3], pa.w);
        acc[4] = fmaf(gh64, acc[4], pb.x);
        acc[5] = fmaf(gh64, acc[5], pb.y);
        acc[6] = fmaf(gh64, acc[6], pb.z);
        acc[7] = fmaf(gh64, acc[7], pb.w);
    }
    const float wl = powg(gh, 63 - lane);
    #pragma unroll
    for (int i = 0; i < 8; ++i) acc[i] *= wl;
    #pragma unroll
    for (int d = 1; d < 64; d <<= 1) {
        #pragma unroll
        for (int i = 0; i < 8; ++i)
            acc[i] += __shfl_xor(acc[i], d, 64);
    }

    // ---- local weighted inclusive scan
    float I[8] = {za.x, za.y, za.z, za.w, zb.x, zb.y, zb.z, zb.w};
    float p = gh;
    #pragma unroll
    for (int d = 1; d < 64; d <<= 1) {
        #pragma unroll
        for (int i = 0; i < 8; ++i) {
            const float up = __shfl_up(I[i], (unsigned)d, 64);
            if (lane >= d) I[i] = fmaf(p, up, I[i]);
        }
        p *= p;
    }

    // ---- W_t
    const float wj = powg(gh, lane);
    float Wt[8];
    #pragma unroll
    for (int i = 0; i < 8; ++i) {
        const float L = __shfl_up(I[i], 1u, 64);
        Wt[i] = fmaf(wj, acc[i], (lane == 0) ? 0.0f : L);
    }

    // ---- pack Qb: B k-column [Qhi(24) | Qlo(24) | Qhi(24) | 0(24)]
    const float q[24] = {xa.x, xa.y, xa.z, xa.w, xb.x, xb.y, xb.z, xb.w,
                         za.x, za.y, za.z, za.w, zb.x, zb.y, zb.z, zb.w,
                         Wt[0], Wt[1], Wt[2], Wt[3], Wt[4], Wt[5], Wt[6], Wt[7]};
    const int tt = t >> 4, c = t & 15;
    #pragma unroll
    for (int s = 0; s < NKS; ++s) {
        #pragma unroll
        for (int ko = 0; ko < 4; ++ko) {
            union { unsigned short u[8]; uint4 v; } pk;
            #pragma unroll
            for (int i = 0; i < 8; ++i) {
                const int k = s * 32 + ko * 8 + i;
                unsigned short o;
                if (k < 24)      o = f2bf(q[k]);
                else if (k < 48) { const unsigned short h = f2bf(q[k - 24]);
                                   o = f2bf(q[k - 24] - bf2f(h)); }
                else if (k < 72) o = f2bf(q[k - 48]);
                else             o = 0;
                pk.u[i] = o;
            }
            *reinterpret_cast<uint4*>(Qb + ((size_t)((tt * NKS + s) * 4 + ko) * 16 + c) * 8) = pk.v;
        }
    }

    // ---- pack Pa: A k-row [Phi(24) | Phi(24) | Plo(24) | 0(24)], 2 rows/lane
    #pragma unroll
    for (int rep = 0; rep < 2; ++rep) {
        const int r = wv * 128 + rep * 64 + lane;
        const float4 e0 = *reinterpret_cast<const float4*>(eta   + (size_t)r * 8);
        const float4 e1 = *reinterpret_cast<const float4*>(eta   + (size_t)r * 8 + 4);
        const float4 c0 = *reinterpret_cast<const float4*>(zeta  + (size_t)r * 8);
        const float4 c1 = *reinterpret_cast<const float4*>(zeta  + (size_t)r * 8 + 4);
        const float4 m0 = *reinterpret_cast<const float4*>(gamma + (size_t)r * 8);
        const float4 m1 = *reinterpret_cast<const float4*>(gamma + (size_t)r * 8 + 4);
        const float pr[24] = {e0.x, e0.y, e0.z, e0.w, e1.x, e1.y, e1.z, e1.w,
                              c0.x, c0.y, c0.z, c0.w, c1.x, c1.y, c1.z, c1.w,
                              m0.x, m0.y, m0.z, m0.w, m1.x, m1.y, m1.z, m1.w};
        const int rt = r >> 4, rw = r & 15;
        #pragma unroll
        for (int s = 0; s < NKS; ++s) {
            #pragma unroll
            for (int ko = 0; ko < 4; ++ko) {
                union { unsigned short u[8]; uint4 v; } pk;
                #pragma unroll
                for (int i = 0; i < 8; ++i) {
                    const int k = s * 32 + ko * 8 + i;
                    unsigned short o;
                    if (k < 24)      o = f2bf(pr[k]);
                    else if (k < 48) o = f2bf(pr[k - 24]);
                    else if (k < 72) { const unsigned short h = f2bf(pr[k - 48]);
                                       o = f2bf(pr[k - 48] - bf2f(h)); }
                    else             o = 0;
                    pk.u[i] = o;
                }
                *reinterpret_cast<uint4*>(Pa + ((size_t)((rt * NKS + s) * 4 + ko) * 16 + rw) * 8) = pk.v;
            }
        }
    }
}

// ---------------------------------------------------------------------------
// KB: wave -> 32x32 output tile (2x2 of 16x16 MFMA tiles). 12 dwordx4 frag
// loads + 12 MFMA + 16 dword stores. No broadcast streams, no recurrence.
// Fallback (wave's G slice not all == G[0]): exact serial replay from t=0.
// ---------------------------------------------------------------------------
extern "C" __global__ __launch_bounds__(256)
void dlm_kb_mfma(const float* __restrict__ Xt, const float* __restrict__ Zt,
                 const float* __restrict__ G, const float* __restrict__ eta,
                 const float* __restrict__ zeta, const float* __restrict__ gamma,
                 const unsigned short* __restrict__ Pa,
                 const unsigned short* __restrict__ Qb,
                 float* __restrict__ out)
{
    const int tid  = threadIdx.x;
    const int wid  = tid >> 6;
    const int lane = tid & 63;
    const int w    = blockIdx.x * 4 + wid;    // 0..8191
    const int rt0  = (w & 127) * 2;           // r-tile pair
    const int tt0  = (w >> 7) * 2;            // t-tile pair
    const int r0   = rt0 * 16;
    const int t0   = tt0 * 16;

    const float G0 = G[0];
    const float gv = G[r0 + (lane & 31)];
    const bool uni = (__ballot(gv == G0) == ~0ull);

    if (uni) {
        const int ko = lane >> 4;      // k-octet 0..3
        const int rc = lane & 15;      // row (A) / col (B)

        bf16x8 af[2][NKS], bf[2][NKS];
        #pragma unroll
        for (int i = 0; i < 2; ++i)
            #pragma unroll
            for (int s = 0; s < NKS; ++s) {
                af[i][s] = *reinterpret_cast<const bf16x8*>(
                    Pa + ((size_t)(((rt0 + i) * NKS + s) * 4 + ko) * 16 + rc) * 8);
                bf[i][s] = *reinterpret_cast<const bf16x8*>(
                    Qb + ((size_t)(((tt0 + i) * NKS + s) * 4 + ko) * 16 + rc) * 8);
            }

        f32x4 accv[2][2];
        #pragma unroll
        for (int i = 0; i < 2; ++i)
            #pragma unroll
            for (int j = 0; j < 2; ++j)
                accv[i][j] = (f32x4){0.f, 0.f, 0.f, 0.f};

        #pragma unroll
        for (int s = 0; s < NKS; ++s)
            #pragma unroll
            for (int i = 0; i < 2; ++i)
                #pragma unroll
                for (int j = 0; j < 2; ++j)
                    accv[i][j] = __builtin_amdgcn_mfma_f32_16x16x32_bf16(
                        af[i][s], bf[j][s], accv[i][j], 0, 0, 0);

        // C/D: col = lane&15, row = (lane>>4)*4 + reg   (m89-verified)
        const int orow = (lane >> 4) * 4;
        const int ocol = lane & 15;
        #pragma unroll
        for (int i = 0; i < 2; ++i)
            #pragma unroll
            for (int j = 0; j < 2; ++j)
                #pragma unroll
                for (int qv = 0; qv < 4; ++qv)
                    out[(size_t)(r0 + 16 * i + orow + qv) * T_STEPS + t0 + 16 * j + ocol]
                        = accv[i][j][qv];
    } else {
        // exact, slow fallback: serial replay from t=0 (correctness-only)
        const int t = t0 + (lane & 31);
        const float4 fxa = *reinterpret_cast<const float4*>(Xt + (size_t)t * 8);
        const float4 fxb = *reinterpret_cast<const float4*>(Xt + (size_t)t * 8 + 4);
        const float4 fza = *reinterpret_cast<const float4*>(Zt + (size_t)t * 8);
        const float4 fzb = *reinterpret_cast<const float4*>(Zt + (size_t)t * 8 + 4);
        for (int rr = 0; rr < 32; ++rr) {
            const int r = r0 + rr;
            const float ghr = sigmoidf_(G[r]);
            const float* __restrict__ gc = gamma + (size_t)r * 8;
            const float* __restrict__ e  = eta   + (size_t)r * 8;
            const float* __restrict__ zc = zeta  + (size_t)r * 8;
            float th = 0.0f, mine = 0.0f;
            for (int s2 = 1; s2 <= t0 + 31; ++s2) {
                const float* __restrict__ zr = Zt + (size_t)(s2 - 1) * 8;
                float b = zr[0] * gc[0];
                #pragma unroll
                for (int qq = 1; qq < 8; ++qq) b = fmaf(zr[qq], gc[qq], b);
                th = fmaf(ghr, th, b);
                mine = (s2 == t) ? th : mine;
            }
            float s = mine;
            s = fmaf(fxa.x, e[0], s);  s = fmaf(fxa.y, e[1], s);
            s = fmaf(fxa.z, e[2], s);  s = fmaf(fxa.w, e[3], s);
            s = fmaf(fxb.x, e[4], s);  s = fmaf(fxb.y, e[5], s);
            s = fmaf(fxb.z, e[6], s);  s = fmaf(fxb.w, e[7], s);
            s = fmaf(fza.x, zc[0], s); s = fmaf(fza.y, zc[1], s);
            s = fmaf(fza.z, zc[2], s); s = fmaf(fza.w, zc[3], s);
            s = fmaf(fzb.x, zc[4], s); s = fmaf(fzb.y, zc[5], s);
            s = fmaf(fzb.z, zc[6], s); s = fmaf(fzb.w, zc[7], s);
            if (lane < 32) out[(size_t)r * T_STEPS + t] = s;
        }
    }
}

// ---------------------------------------------------------------------------
extern "C" void kernel_launch(void* const* d_in, const int* in_sizes, int n_in,
                              void* d_out, int out_size, void* d_ws, size_t ws_size,
                              hipStream_t stream)
{
    const float* Xt    = (const float*)d_in[0];
    const float* Zt    = (const float*)d_in[1];
    const float* G     = (const float*)d_in[2];
    const float* eta   = (const float*)d_in[3];
    const float* zeta  = (const float*)d_in[4];
    const float* gamma = (const float*)d_in[5];
    float* out = (float*)d_out;

    // ws: Pa (786 KB bf16 A-fragments) | Qb (393 KB bf16 B-fragments)
    unsigned short* Pa = (unsigned short*)d_ws;
    unsigned short* Qb = Pa + PA_ELEMS;

    const dim3 blk(256);
    dlm_k1_pack<<<dim3(8),    blk, 0, stream>>>(Xt, Zt, G, eta, zeta, gamma, Pa, Qb);
    dlm_kb_mfma<<<dim3(2048), blk, 0, stream>>>(Xt, Zt, G, eta, zeta, gamma, Pa, Qb, out);
}

// Round 13
// 20.403 us; speedup vs baseline: 2.5210x; 1.3131x over previous
//
#include <hip/hip_runtime.h>
#include <math.h>

typedef float  f32x4  __attribute__((ext_vector_type(4)));
typedef short  bf16x8 __attribute__((ext_vector_type(8)));

namespace {
constexpr int R_RUNS  = 4096;
constexpr int T_STEPS = 2048;
constexpr int NKS     = 3;   // three K=32 MFMA steps (K=96, 72 used)
constexpr size_t PA_ELEMS = (size_t)(R_RUNS / 16) * NKS * 4 * 16 * 8;  // 393216 ushort
}

__device__ __forceinline__ float sigmoidf_(float x) { return 1.0f / (1.0f + expf(-x)); }

__device__ __forceinline__ unsigned short f2bf(float f) {
    unsigned u = __float_as_uint(f);
    unsigned r = (u + 0x7FFFu + ((u >> 16) & 1u)) >> 16;
    return (unsigned short)r;
}
__device__ __forceinline__ float bf2f(unsigned short h) {
    return __uint_as_float(((unsigned)h) << 16);
}
__device__ __forceinline__ float powg(float gh, int e) {   // gh^e, e in [0,63]
    float w = 1.f, p = gh;
    #pragma unroll
    for (int i = 0; i < 6; ++i) { w *= ((e >> i) & 1) ? p : 1.f; p *= p; }
    return w;
}

// ---------------------------------------------------------------------------
// K1 (24 blocks):
//   blocks 0-7  (32 waves): W-scan (verified R10-R12) + Qb pack (B fragments).
//   blocks 8-23 (64 waves): Pa pack (A fragments) — independent of W, runs
//                           concurrently. 64 runs per wave, 1 per lane.
// Fragment order: lane l of KB reads octet ko=l>>4, row/col=l&15 as dwordx4.
// A k-schedule [Phi|Phi|Plo|0]; B k-schedule [Qhi|Qlo|Qhi|0]  (R12-verified).
// ---------------------------------------------------------------------------
extern "C" __global__ __launch_bounds__(256)
void dlm_k1_pack(const float* __restrict__ Xt, const float* __restrict__ Zt,
                 const float* __restrict__ G, const float* __restrict__ eta,
                 const float* __restrict__ zeta, const float* __restrict__ gamma,
                 unsigned short* __restrict__ Pa, unsigned short* __restrict__ Qb)
{
    const int tid  = threadIdx.x;
    const int wid  = tid >> 6;
    const int lane = tid & 63;

    if (blockIdx.x >= 8) {
        // ---------------- Pa pack: run r = pw*64 + lane ----------------
        const int pw = (blockIdx.x - 8) * 4 + wid;   // 0..63
        const int r  = pw * 64 + lane;
        const float4 e0 = *reinterpret_cast<const float4*>(eta   + (size_t)r * 8);
        const float4 e1 = *reinterpret_cast<const float4*>(eta   + (size_t)r * 8 + 4);
        const float4 c0 = *reinterpret_cast<const float4*>(zeta  + (size_t)r * 8);
        const float4 c1 = *reinterpret_cast<const float4*>(zeta  + (size_t)r * 8 + 4);
        const float4 m0 = *reinterpret_cast<const float4*>(gamma + (size_t)r * 8);
        const float4 m1 = *reinterpret_cast<const float4*>(gamma + (size_t)r * 8 + 4);
        const float pr[24] = {e0.x, e0.y, e0.z, e0.w, e1.x, e1.y, e1.z, e1.w,
                              c0.x, c0.y, c0.z, c0.w, c1.x, c1.y, c1.z, c1.w,
                              m0.x, m0.y, m0.z, m0.w, m1.x, m1.y, m1.z, m1.w};
        const int rt = r >> 4, rw = r & 15;
        #pragma unroll
        for (int s = 0; s < NKS; ++s) {
            #pragma unroll
            for (int ko = 0; ko < 4; ++ko) {
                union { unsigned short u[8]; uint4 v; } pk;
                #pragma unroll
                for (int i = 0; i < 8; ++i) {
                    const int k = s * 32 + ko * 8 + i;
                    unsigned short o;
                    if (k < 24)      o = f2bf(pr[k]);
                    else if (k < 48) o = f2bf(pr[k - 24]);
                    else if (k < 72) { const unsigned short h = f2bf(pr[k - 48]);
                                       o = f2bf(pr[k - 48] - bf2f(h)); }
                    else             o = 0;
                    pk.u[i] = o;
                }
                *reinterpret_cast<uint4*>(Pa + ((size_t)((rt * NKS + s) * 4 + ko) * 16 + rw) * 8) = pk.v;
            }
        }
        return;
    }

    // ---------------- W-scan + Qb pack (blocks 0-7) ----------------
    const int wv = blockIdx.x * 4 + wid;   // 0..31
    const int t  = wv * 64 + lane;

    const float gh = sigmoidf_(G[0]);
    float gh64 = gh;
    #pragma unroll
    for (int i = 0; i < 6; ++i) gh64 *= gh64;

    const float4 za = *reinterpret_cast<const float4*>(Zt + (size_t)t * 8);
    const float4 zb = *reinterpret_cast<const float4*>(Zt + (size_t)t * 8 + 4);
    const float4 xa = *reinterpret_cast<const float4*>(Xt + (size_t)t * 8);
    const float4 xb = *reinterpret_cast<const float4*>(Xt + (size_t)t * 8 + 4);

    float acc[8] = {0.f, 0.f, 0.f, 0.f, 0.f, 0.f, 0.f, 0.f};
    for (int m = 0; m < wv; ++m) {
        const float* __restrict__ zp = Zt + (size_t)(m * 64 + lane) * 8;
        const float4 pa = *reinterpret_cast<const float4*>(zp);
        const float4 pb = *reinterpret_cast<const float4*>(zp + 4);
        acc[0] = fmaf(gh64, acc[0], pa.x);
        acc[1] = fmaf(gh64, acc[1], pa.y);
        acc[2] = fmaf(gh64, acc[2], pa.z);
        acc[3] = fmaf(gh64, acc[3], pa.w);
        acc[4] = fmaf(gh64, acc[4], pb.x);
        acc[5] = fmaf(gh64, acc[5], pb.y);
        acc[6] = fmaf(gh64, acc[6], pb.z);
        acc[7] = fmaf(gh64, acc[7], pb.w);
    }
    const float wl = powg(gh, 63 - lane);
    #pragma unroll
    for (int i = 0; i < 8; ++i) acc[i] *= wl;
    #pragma unroll
    for (int d = 1; d < 64; d <<= 1) {
        #pragma unroll
        for (int i = 0; i < 8; ++i)
            acc[i] += __shfl_xor(acc[i], d, 64);
    }

    float I[8] = {za.x, za.y, za.z, za.w, zb.x, zb.y, zb.z, zb.w};
    float p = gh;
    #pragma unroll
    for (int d = 1; d < 64; d <<= 1) {
        #pragma unroll
        for (int i = 0; i < 8; ++i) {
            const float up = __shfl_up(I[i], (unsigned)d, 64);
            if (lane >= d) I[i] = fmaf(p, up, I[i]);
        }
        p *= p;
    }

    const float wj = powg(gh, lane);
    float Wt[8];
    #pragma unroll
    for (int i = 0; i < 8; ++i) {
        const float L = __shfl_up(I[i], 1u, 64);
        Wt[i] = fmaf(wj, acc[i], (lane == 0) ? 0.0f : L);
    }

    const float q[24] = {xa.x, xa.y, xa.z, xa.w, xb.x, xb.y, xb.z, xb.w,
                         za.x, za.y, za.z, za.w, zb.x, zb.y, zb.z, zb.w,
                         Wt[0], Wt[1], Wt[2], Wt[3], Wt[4], Wt[5], Wt[6], Wt[7]};
    const int tt = t >> 4, c = t & 15;
    #pragma unroll
    for (int s = 0; s < NKS; ++s) {
        #pragma unroll
        for (int ko = 0; ko < 4; ++ko) {
            union { unsigned short u[8]; uint4 v; } pk;
            #pragma unroll
            for (int i = 0; i < 8; ++i) {
                const int k = s * 32 + ko * 8 + i;
                unsigned short o;
                if (k < 24)      o = f2bf(q[k]);
                else if (k < 48) { const unsigned short h = f2bf(q[k - 24]);
                                   o = f2bf(q[k - 24] - bf2f(h)); }
                else if (k < 72) o = f2bf(q[k - 48]);
                else             o = 0;
                pk.u[i] = o;
            }
            *reinterpret_cast<uint4*>(Qb + ((size_t)((tt * NKS + s) * 4 + ko) * 16 + c) * 8) = pk.v;
        }
    }
}

// ---------------------------------------------------------------------------
// KB: wave -> 32x32 output tile (2x2 of 16x16 MFMA). 12 dwordx4 frag loads +
// 12 MFMA + 16 NONTEMPORAL dword stores (bypass L2 write-allocate/RFO —
// output is write-once-never-read).
// Fallback (wave's G slice not all == G[0]): exact serial replay from t=0.
// ---------------------------------------------------------------------------
extern "C" __global__ __launch_bounds__(256)
void dlm_kb_mfma(const float* __restrict__ Xt, const float* __restrict__ Zt,
                 const float* __restrict__ G, const float* __restrict__ eta,
                 const float* __restrict__ zeta, const float* __restrict__ gamma,
                 const unsigned short* __restrict__ Pa,
                 const unsigned short* __restrict__ Qb,
                 float* __restrict__ out)
{
    const int tid  = threadIdx.x;
    const int wid  = tid >> 6;
    const int lane = tid & 63;
    const int w    = blockIdx.x * 4 + wid;    // 0..8191
    const int rt0  = (w & 127) * 2;           // r-tile pair
    const int tt0  = (w >> 7) * 2;            // t-tile pair
    const int r0   = rt0 * 16;
    const int t0   = tt0 * 16;

    const float G0 = G[0];
    const float gv = G[r0 + (lane & 31)];
    const bool uni = (__ballot(gv == G0) == ~0ull);

    if (uni) {
        const int ko = lane >> 4;
        const int rc = lane & 15;

        bf16x8 af[2][NKS], bfr[2][NKS];
        #pragma unroll
        for (int i = 0; i < 2; ++i)
            #pragma unroll
            for (int s = 0; s < NKS; ++s) {
                af[i][s] = *reinterpret_cast<const bf16x8*>(
                    Pa + ((size_t)(((rt0 + i) * NKS + s) * 4 + ko) * 16 + rc) * 8);
                bfr[i][s] = *reinterpret_cast<const bf16x8*>(
                    Qb + ((size_t)(((tt0 + i) * NKS + s) * 4 + ko) * 16 + rc) * 8);
            }

        f32x4 accv[2][2];
        #pragma unroll
        for (int i = 0; i < 2; ++i)
            #pragma unroll
            for (int j = 0; j < 2; ++j)
                accv[i][j] = (f32x4){0.f, 0.f, 0.f, 0.f};

        #pragma unroll
        for (int s = 0; s < NKS; ++s)
            #pragma unroll
            for (int i = 0; i < 2; ++i)
                #pragma unroll
                for (int j = 0; j < 2; ++j)
                    accv[i][j] = __builtin_amdgcn_mfma_f32_16x16x32_bf16(
                        af[i][s], bfr[j][s], accv[i][j], 0, 0, 0);

        // C/D: col = lane&15, row = (lane>>4)*4 + reg
        const int orow = (lane >> 4) * 4;
        const int ocol = lane & 15;
        #pragma unroll
        for (int i = 0; i < 2; ++i)
            #pragma unroll
            for (int j = 0; j < 2; ++j)
                #pragma unroll
                for (int qv = 0; qv < 4; ++qv)
                    __builtin_nontemporal_store(
                        accv[i][j][qv],
                        &out[(size_t)(r0 + 16 * i + orow + qv) * T_STEPS + t0 + 16 * j + ocol]);
    } else {
        // exact, slow fallback: serial replay from t=0 (correctness-only)
        const int t = t0 + (lane & 31);
        const float4 fxa = *reinterpret_cast<const float4*>(Xt + (size_t)t * 8);
        const float4 fxb = *reinterpret_cast<const float4*>(Xt + (size_t)t * 8 + 4);
        const float4 fza = *reinterpret_cast<const float4*>(Zt + (size_t)t * 8);
        const float4 fzb = *reinterpret_cast<const float4*>(Zt + (size_t)t * 8 + 4);
        for (int rr = 0; rr < 32; ++rr) {
            const int r = r0 + rr;
            const float ghr = sigmoidf_(G[r]);
            const float* __restrict__ gc = gamma + (size_t)r * 8;
            const float* __restrict__ e  = eta   + (size_t)r * 8;
            const float* __restrict__ zc = zeta  + (size_t)r * 8;
            float th = 0.0f, mine = 0.0f;
            for (int s2 = 1; s2 <= t0 + 31; ++s2) {
                const float* __restrict__ zr = Zt + (size_t)(s2 - 1) * 8;
                float b = zr[0] * gc[0];
                #pragma unroll
                for (int qq = 1; qq < 8; ++qq) b = fmaf(zr[qq], gc[qq], b);
                th = fmaf(ghr, th, b);
                mine = (s2 == t) ? th : mine;
            }
            float s = mine;
            s = fmaf(fxa.x, e[0], s);  s = fmaf(fxa.y, e[1], s);
            s = fmaf(fxa.z, e[2], s);  s = fmaf(fxa.w, e[3], s);
            s = fmaf(fxb.x, e[4], s);  s = fmaf(fxb.y, e[5], s);
            s = fmaf(fxb.z, e[6], s);  s = fmaf(fxb.w, e[7], s);
            s = fmaf(fza.x, zc[0], s); s = fmaf(fza.y, zc[1], s);
            s = fmaf(fza.z, zc[2], s); s = fmaf(fza.w, zc[3], s);
            s = fmaf(fzb.x, zc[4], s); s = fmaf(fzb.y, zc[5], s);
            s = fmaf(fzb.z, zc[6], s); s = fmaf(fzb.w, zc[7], s);
            if (lane < 32) out[(size_t)r * T_STEPS + t] = s;
        }
    }
}

// ---------------------------------------------------------------------------
extern "C" void kernel_launch(void* const* d_in, const int* in_sizes, int n_in,
                              void* d_out, int out_size, void* d_ws, size_t ws_size,
                              hipStream_t stream)
{
    const float* Xt    = (const float*)d_in[0];
    const float* Zt    = (const float*)d_in[1];
    const float* G     = (const float*)d_in[2];
    const float* eta   = (const float*)d_in[3];
    const float* zeta  = (const float*)d_in[4];
    const float* gamma = (const float*)d_in[5];
    float* out = (float*)d_out;

    unsigned short* Pa = (unsigned short*)d_ws;
    unsigned short* Qb = Pa + PA_ELEMS;

    const dim3 blk(256);
    dlm_k1_pack<<<dim3(24),   blk, 0, stream>>>(Xt, Zt, G, eta, zeta, gamma, Pa, Qb);
    dlm_kb_mfma<<<dim3(2048), blk, 0, stream>>>(Xt, Zt, G, eta, zeta, gamma, Pa, Qb, out);
}